// Round 2
// baseline (1959.434 us; speedup 1.0000x reference)
//
#include <hip/hip_runtime.h>
#include <hip/hip_bf16.h>
#include <stdint.h>

typedef __attribute__((ext_vector_type(8))) short short8;
typedef __attribute__((ext_vector_type(4))) short short4v;
typedef __attribute__((ext_vector_type(4))) float floatx4;

#define NPTS 400000
#define KOFF 27

// Split fp32 v into bf16 hi (truncate) + bf16 lo (truncated residual).
// v ~= hi + lo with relative error ~2^-16.
__device__ __forceinline__ void split_bits(float v, short& hi, short& lo) {
    union U { float f; unsigned int u; };
    U a; a.f = v;
    hi = (short)(a.u >> 16);
    U h; h.u = a.u & 0xFFFF0000u;
    U b; b.f = v - h.f;   // exact (same exponent)
    lo = (short)(b.u >> 16);
}

__global__ __launch_bounds__(256) void split_x_kernel(const float* __restrict__ x,
                                                      short* __restrict__ xh,
                                                      short* __restrict__ xl,
                                                      int n4) {
    int t = blockIdx.x * 256 + threadIdx.x;
    if (t >= n4) return;
    floatx4 v = *(const floatx4*)(x + (size_t)t * 4);
    short4v hv, lv;
#pragma unroll
    for (int j = 0; j < 4; ++j) {
        short h, l;
        split_bits(v[j], h, l);
        hv[j] = h; lv[j] = l;
    }
    *(short4v*)(xh + (size_t)t * 4) = hv;
    *(short4v*)(xl + (size_t)t * 4) = lv;
}

// W input: [k][cin][cout] fp32 (cout contiguous). Output: [k][cout][cin] bf16 hi/lo
// so the MFMA B-fragment (8 consecutive cin for fixed cout) is one 16B load.
__global__ __launch_bounds__(256) void prep_w_kernel(const float* __restrict__ W,
                                                     short* __restrict__ wh,
                                                     short* __restrict__ wl) {
    int t = blockIdx.x * 256 + threadIdx.x;  // over 27*64*64, [k][cout][cin]
    int k = t >> 12;
    int cout = (t >> 6) & 63;
    int cin = t & 63;
    float v = W[(k << 12) + (cin << 6) + cout];
    short h, l;
    split_bits(v, h, l);
    wh[t] = h;
    wl[t] = l;
}

// One workgroup = 128 points. 4 waves; wave w owns points [base, base+32).
// Wave tiles: 2 M-tiles (16 pts) x 4 N-tiles (16 couts), mfma_f32_16x16x32_bf16.
// Contraction dim = (k, cin) = 27*64, stepped 32 at a time.
// A-frag: lane holds A[row=lane&15][kk=(lane>>4)*8 + 0..7] -> 16B gathered load.
// B-frag: lane holds B[kk][col=lane&15]; W stored [k][cout][cin] -> 16B load.
// D: col=lane&15, row=(lane>>4)*4+reg  (guide m89, HW-verified).
template <int LAYER>
__global__ __launch_bounds__(256, 3) void conv_layer(
        const short* __restrict__ xh, const short* __restrict__ xl,
        const short* __restrict__ wh, const short* __restrict__ wl,
        const float* __restrict__ bias,
        const int* __restrict__ nidx, const int* __restrict__ nmask,
        const float* __restrict__ xres,
        short* __restrict__ oh, short* __restrict__ ol,
        float* __restrict__ outf) {
    const int tid = threadIdx.x;
    const int wv = tid >> 6;
    const int lane = tid & 63;
    const int row = lane & 15;
    const int kg = lane >> 4;
    const int base = blockIdx.x * 128 + wv * 32;

    floatx4 acc[2][4];
#pragma unroll
    for (int mt = 0; mt < 2; ++mt)
#pragma unroll
        for (int nt = 0; nt < 4; ++nt)
            acc[mt][nt] = (floatx4)0.0f;

#pragma unroll 3
    for (int k = 0; k < KOFF; ++k) {
        short8 ah[2][2], al[2][2];  // [m-tile][cin-chunk]
#pragma unroll
        for (int mt = 0; mt < 2; ++mt) {
            const int p = base + mt * 16 + row;
            const int id = nidx[p * KOFF + k];
            const bool m = nmask[p * KOFF + k] != 0;  // mask arrives as int32
            ah[mt][0] = (short8)0; ah[mt][1] = (short8)0;
            al[mt][0] = (short8)0; al[mt][1] = (short8)0;
            if (m) {  // exec-masked: masked-off lanes issue no memory traffic
                const short* ph = xh + ((size_t)id << 6) + (kg << 3);
                const short* pl = xl + ((size_t)id << 6) + (kg << 3);
                ah[mt][0] = *(const short8*)(ph);
                ah[mt][1] = *(const short8*)(ph + 32);
                al[mt][0] = *(const short8*)(pl);
                al[mt][1] = *(const short8*)(pl + 32);
            }
        }
        const short* wbh = wh + (k << 12);
        const short* wbl = wl + (k << 12);
#pragma unroll
        for (int s = 0; s < 2; ++s) {
#pragma unroll
            for (int nt = 0; nt < 4; ++nt) {
                const int coff = ((nt * 16 + row) << 6) + (s << 5) + (kg << 3);
                const short8 bh = *(const short8*)(wbh + coff);
                const short8 bl = *(const short8*)(wbl + coff);
#pragma unroll
                for (int mt = 0; mt < 2; ++mt) {
                    // 3-term split product: xh*Wh + xh*Wl + xl*Wh
                    acc[mt][nt] = __builtin_amdgcn_mfma_f32_16x16x32_bf16(ah[mt][s], bh, acc[mt][nt], 0, 0, 0);
                    acc[mt][nt] = __builtin_amdgcn_mfma_f32_16x16x32_bf16(ah[mt][s], bl, acc[mt][nt], 0, 0, 0);
                    acc[mt][nt] = __builtin_amdgcn_mfma_f32_16x16x32_bf16(al[mt][s], bh, acc[mt][nt], 0, 0, 0);
                }
            }
        }
    }

    // Epilogue. D layout: col=lane&15, row=(lane>>4)*4 + i.
    const int col = lane & 15;
#pragma unroll
    for (int mt = 0; mt < 2; ++mt) {
#pragma unroll
        for (int nt = 0; nt < 4; ++nt) {
            const float bc = bias[nt * 16 + col];
#pragma unroll
            for (int i = 0; i < 4; ++i) {
                const int p = base + mt * 16 + kg * 4 + i;
                const int c = nt * 16 + col;
                float v = acc[mt][nt][i] + bc;
                if (LAYER == 0) {
                    v = fmaxf(v, 0.0f);
                    short h, l;
                    split_bits(v, h, l);
                    oh[(size_t)p * 64 + c] = h;
                    ol[(size_t)p * 64 + c] = l;
                } else {
                    v += xres[(size_t)p * 64 + c];
                    outf[(size_t)p * 64 + c] = v;
                }
            }
        }
    }
}

extern "C" void kernel_launch(void* const* d_in, const int* in_sizes, int n_in,
                              void* d_out, int out_size, void* d_ws, size_t ws_size,
                              hipStream_t stream) {
    const float* x  = (const float*)d_in[0];
    const float* W0 = (const float*)d_in[1];
    const float* b0 = (const float*)d_in[2];
    const float* W1 = (const float*)d_in[3];
    const float* b1 = (const float*)d_in[4];
    const int* nidx = (const int*)d_in[5];
    const int* nmask = (const int*)d_in[6];  // jax bool -> harness int32
    float* out = (float*)d_out;

    // Workspace layout (~205.7 MB total):
    char* ws = (char*)d_ws;
    const size_t rowBytes = (size_t)NPTS * 64 * sizeof(short);  // 51.2 MB each
    short* xh = (short*)(ws + 0 * rowBytes);
    short* xl = (short*)(ws + 1 * rowBytes);
    short* hh = (short*)(ws + 2 * rowBytes);
    short* hl = (short*)(ws + 3 * rowBytes);
    const size_t wBytes = (size_t)KOFF * 64 * 64 * sizeof(short);  // 221 KB each
    char* wsw = ws + 4 * rowBytes;
    short* w0h = (short*)(wsw + 0 * wBytes);
    short* w0l = (short*)(wsw + 1 * wBytes);
    short* w1h = (short*)(wsw + 2 * wBytes);
    short* w1l = (short*)(wsw + 3 * wBytes);

    // N*64/4 = 6.4M quads -> 25000 blocks; 27*64*64/256 = 432 blocks; N/128 = 3125.
    split_x_kernel<<<25000, 256, 0, stream>>>(x, xh, xl, NPTS * 64 / 4);
    prep_w_kernel<<<432, 256, 0, stream>>>(W0, w0h, w0l);
    prep_w_kernel<<<432, 256, 0, stream>>>(W1, w1h, w1l);

    conv_layer<0><<<3125, 256, 0, stream>>>(xh, xl, w0h, w0l, b0, nidx, nmask,
                                            nullptr, hh, hl, nullptr);
    conv_layer<1><<<3125, 256, 0, stream>>>(hh, hl, w1h, w1l, b1, nidx, nmask,
                                            x, nullptr, nullptr, out);
}

// Round 3
// 1130.684 us; speedup vs baseline: 1.7330x; 1.7330x over previous
//
#include <hip/hip_runtime.h>
#include <stdint.h>

typedef __attribute__((ext_vector_type(8))) short short8;
typedef __attribute__((ext_vector_type(4))) float floatx4;
typedef __attribute__((ext_vector_type(4))) int int4v;
typedef __attribute__((ext_vector_type(4))) short short4v;

#define NPTS 400000
#define KOFF 27

// fp32 -> bf16 round-to-nearest-even
__device__ __forceinline__ unsigned short f2bf(float v) {
    union { float f; unsigned int u; } a; a.f = v;
    unsigned int r = a.u + 0x7FFFu + ((a.u >> 16) & 1u);
    return (unsigned short)(r >> 16);
}

__global__ __launch_bounds__(256) void cvt_x_kernel(const float* __restrict__ x,
                                                    unsigned short* __restrict__ xb,
                                                    int n4) {
    int t = blockIdx.x * 256 + threadIdx.x;
    if (t >= n4) return;
    floatx4 v = *(const floatx4*)(x + (size_t)t * 4);
    short4v o;
#pragma unroll
    for (int j = 0; j < 4; ++j) o[j] = (short)f2bf(v[j]);
    *(short4v*)(xb + (size_t)t * 4) = o;
}

// pack neighbor idx + mask: bit31 = mask, bits 0..18 = idx (N < 2^19)
__global__ __launch_bounds__(256) void pack_kernel(const int* __restrict__ idx,
                                                   const int* __restrict__ msk,
                                                   int* __restrict__ pk, int n4) {
    int t = blockIdx.x * 256 + threadIdx.x;
    if (t >= n4) return;
    int4v a = *(const int4v*)(idx + (size_t)t * 4);
    int4v m = *(const int4v*)(msk + (size_t)t * 4);
    int4v o;
#pragma unroll
    for (int j = 0; j < 4; ++j) o[j] = a[j] | (m[j] ? (int)0x80000000 : 0);
    *(int4v*)(pk + (size_t)t * 4) = o;
}

// W input: [k][cin][cout] fp32 -> [k][cout][cin] bf16 (B-fragment = contiguous 16B)
__global__ __launch_bounds__(256) void cvt_w_kernel(const float* __restrict__ W,
                                                    unsigned short* __restrict__ wb) {
    int t = blockIdx.x * 256 + threadIdx.x;  // [k][cout][cin]
    int k = t >> 12, cout = (t >> 6) & 63, cin = t & 63;
    wb[t] = f2bf(W[(k << 12) + (cin << 6) + cout]);
}

// One workgroup = 128 points, 4 waves x 32 points. Wave: 2 M-tiles x 4 N-tiles of
// mfma_f32_16x16x32_bf16, contraction over (k=27, cin=64).
// Software pipeline: pack prefetched 2 ahead, gather 1 ahead -> the dependent
// chain pack-load -> gather -> MFMA is spread over 2 iterations and hides
// under the MFMA stream of the current iteration.
// A-frag: lane(row=lane&15, kg=lane>>4) holds A[row][s*32 + kg*8 + j].
// B-frag: col=lane&15 from wb[k][cout][cin]. D: col=lane&15, row=kg*4+reg (m89).
template <int LAYER>
__global__ __launch_bounds__(256, 4) void conv_layer(
        const unsigned short* __restrict__ xb,
        const unsigned short* __restrict__ wb,
        const float* __restrict__ bias,
        const int* __restrict__ pk,
        const float* __restrict__ xres,
        unsigned short* __restrict__ ob,
        float* __restrict__ outf) {
    const int tid = threadIdx.x;
    const int wv = tid >> 6, lane = tid & 63;
    const int row = lane & 15, kg = lane >> 4;
    const int base = blockIdx.x * 128 + wv * 32;
    const int pr0 = (base + row) * KOFF;
    const int pr1 = (base + 16 + row) * KOFF;

    floatx4 acc[2][4];
#pragma unroll
    for (int mt = 0; mt < 2; ++mt)
#pragma unroll
        for (int nt = 0; nt < 4; ++nt) acc[mt][nt] = (floatx4)0.0f;

    short8 Ac[2][2], An[2][2];
    int pg[2], pl[2] = {0, 0};

    // prologue: pack(0) -> gather(0); pack(1)
    pg[0] = pk[pr0];
    pg[1] = pk[pr1];
#pragma unroll
    for (int mt = 0; mt < 2; ++mt) {
        Ac[mt][0] = (short8)0; Ac[mt][1] = (short8)0;
        if (pg[mt] < 0) {  // exec-masked: no memory traffic for masked lanes
            const unsigned short* p = xb + ((size_t)(pg[mt] & 0x7FFFFFFF) << 6) + (kg << 3);
            Ac[mt][0] = *(const short8*)p;
            Ac[mt][1] = *(const short8*)(p + 32);
        }
    }
    pg[0] = pk[pr0 + 1];
    pg[1] = pk[pr1 + 1];

#pragma unroll
    for (int k = 0; k < KOFF; ++k) {
        // gather A for k+1 (pack already resident from previous iteration)
        if (k < KOFF - 1) {
#pragma unroll
            for (int mt = 0; mt < 2; ++mt) {
                An[mt][0] = (short8)0; An[mt][1] = (short8)0;
                if (pg[mt] < 0) {
                    const unsigned short* p = xb + ((size_t)(pg[mt] & 0x7FFFFFFF) << 6) + (kg << 3);
                    An[mt][0] = *(const short8*)p;
                    An[mt][1] = *(const short8*)(p + 32);
                }
            }
        }
        // issue pack load for k+2
        if (k < KOFF - 2) {
            pl[0] = pk[pr0 + k + 2];
            pl[1] = pk[pr1 + k + 2];
        }
        const unsigned short* wk = wb + (k << 12);
#pragma unroll
        for (int s = 0; s < 2; ++s) {
#pragma unroll
            for (int nt = 0; nt < 4; ++nt) {
                const short8 b = *(const short8*)(wk + ((nt * 16 + row) << 6) + (s << 5) + (kg << 3));
                acc[0][nt] = __builtin_amdgcn_mfma_f32_16x16x32_bf16(Ac[0][s], b, acc[0][nt], 0, 0, 0);
                acc[1][nt] = __builtin_amdgcn_mfma_f32_16x16x32_bf16(Ac[1][s], b, acc[1][nt], 0, 0, 0);
            }
        }
        // rotate pipeline (full unroll -> pure register renaming)
#pragma unroll
        for (int mt = 0; mt < 2; ++mt) {
            Ac[mt][0] = An[mt][0];
            Ac[mt][1] = An[mt][1];
            pg[mt] = pl[mt];
        }
    }

    // Epilogue. D layout: col=lane&15, row=kg*4+i.
    const int col = row;
#pragma unroll
    for (int mt = 0; mt < 2; ++mt) {
#pragma unroll
        for (int nt = 0; nt < 4; ++nt) {
            const float bc = bias[nt * 16 + col];
#pragma unroll
            for (int i = 0; i < 4; ++i) {
                const size_t p = base + mt * 16 + kg * 4 + i;
                const int c = nt * 16 + col;
                float v = acc[mt][nt][i] + bc;
                if (LAYER == 0) {
                    ob[p * 64 + c] = f2bf(fmaxf(v, 0.0f));
                } else {
                    outf[p * 64 + c] = v + xres[p * 64 + c];
                }
            }
        }
    }
}

extern "C" void kernel_launch(void* const* d_in, const int* in_sizes, int n_in,
                              void* d_out, int out_size, void* d_ws, size_t ws_size,
                              hipStream_t stream) {
    const float* x  = (const float*)d_in[0];
    const float* W0 = (const float*)d_in[1];
    const float* b0 = (const float*)d_in[2];
    const float* W1 = (const float*)d_in[3];
    const float* b1 = (const float*)d_in[4];
    const int* nidx = (const int*)d_in[5];
    const int* nmask = (const int*)d_in[6];  // jax bool -> harness int32
    float* out = (float*)d_out;

    // Workspace: xb 51.2MB | hb 51.2MB | pk 43.2MB | w0b 221KB | w1b 221KB  (~146MB)
    char* ws = (char*)d_ws;
    const size_t rowBytes = (size_t)NPTS * 64 * sizeof(short);          // 51.2 MB
    const size_t pkBytes  = (size_t)NPTS * KOFF * sizeof(int);          // 43.2 MB
    const size_t wBytes   = (size_t)KOFF * 64 * 64 * sizeof(short);     // 221 KB
    unsigned short* xb = (unsigned short*)(ws);
    unsigned short* hb = (unsigned short*)(ws + rowBytes);
    int* pkbuf         = (int*)(ws + 2 * rowBytes);
    unsigned short* w0b = (unsigned short*)(ws + 2 * rowBytes + pkBytes);
    unsigned short* w1b = (unsigned short*)(ws + 2 * rowBytes + pkBytes + wBytes);

    cvt_x_kernel<<<25000, 256, 0, stream>>>(x, xb, NPTS * 64 / 4);          // 6.4M quads
    pack_kernel<<<10547, 256, 0, stream>>>(nidx, nmask, pkbuf, NPTS * KOFF / 4);
    cvt_w_kernel<<<432, 256, 0, stream>>>(W0, w0b);
    cvt_w_kernel<<<432, 256, 0, stream>>>(W1, w1b);

    conv_layer<0><<<3125, 256, 0, stream>>>(xb, w0b, b0, pkbuf, nullptr, hb, nullptr);
    conv_layer<1><<<3125, 256, 0, stream>>>(hb, w1b, b1, pkbuf, x, nullptr, out);
}